// Round 1
// baseline (502.932 us; speedup 1.0000x reference)
//
#include <hip/hip_runtime.h>
#include <stdint.h>

typedef __attribute__((ext_vector_type(8))) short short8;
typedef __attribute__((ext_vector_type(4))) float floatx4;

__device__ __forceinline__ unsigned short f2bf(float x) {
  unsigned int u = __float_as_uint(x);
  u += 0x7fffu + ((u >> 16) & 1u);   // RNE
  return (unsigned short)(u >> 16);
}
__device__ __forceinline__ float bf2f(unsigned short b) {
  return __uint_as_float(((unsigned int)b) << 16);
}

__device__ __forceinline__ void gload_lds16(const void* g, void* lds) {
  __builtin_amdgcn_global_load_lds(
      (const __attribute__((address_space(1))) unsigned int*)g,
      (__attribute__((address_space(3))) unsigned int*)lds, 16, 0, 0);
}

// Convert W [K][256] fp32 row-major -> swizzled bf16 B^T stream:
// byte stream = [kc][n][cp][j], where slot cp holds logical 16B chunk c = cp^(n&7),
// i.e. element j of k = kc*64 + c*8 + j, column n.
__global__ void wcvt_kernel(const float* __restrict__ W, unsigned short* __restrict__ out,
                            int total) {
  int u = blockIdx.x * 256 + threadIdx.x;
  if (u >= total) return;
  int j  = u & 7;
  int cp = (u >> 3) & 7;
  int n  = (u >> 6) & 255;
  int kc = u >> 14;
  int k  = kc * 64 + (((cp ^ (n & 7)) << 3) | j);
  out[u] = f2bf(W[k * 256 + n]);
}

// LDS: layer-1 A-staging (+index cache) unioned with X (layer outputs); B staging
// buffer reused for W1/W2 chunks and (after layer 2) overlaid with W3 fp32.
// Total = 32768 + 32768 = 65536 B -> 2 blocks/CU (128 KB of 160 KB).
union SMemU {
  struct {
    short8 A[64 * 8];      // [row][chunk-slot], slot = c ^ (row&7); 8 KB
    int ioff[128];         // dst nodes [0,64), src nodes [64,128)
  } l1;
  unsigned short X[64 * 256]; // bf16, 16B-chunk swizzle: slot = c ^ (row&7)
};
struct SMem {
  SMemU u;              // 32 KB
  short8 B[256 * 8];    // 32 KB: [n][chunk-slot], slot = c ^ (n&7); w3 overlay in L3
};

__global__ __launch_bounds__(256, 2)
void edge_mlp_kernel(const float* __restrict__ h,
                     const int* __restrict__ dst,
                     const int* __restrict__ src,
                     const unsigned short* __restrict__ W1T,
                     const unsigned short* __restrict__ W2T,
                     const float* __restrict__ W3,
                     float* __restrict__ out) {
  __shared__ SMem sm;
  const int t    = threadIdx.x;
  const int lane = t & 63;
  const int w    = t >> 6;       // wave id 0..3 -> N columns w*64..w*64+64
  const int lq   = lane >> 4;    // quad
  const int lm   = lane & 15;
  const int m0   = blockIdx.x * 64;

  if (t < 64)       sm.u.l1.ioff[t] = dst[m0 + t];
  else if (t < 128) sm.u.l1.ioff[t] = src[m0 + t - 64];

  floatx4 acc[4][4];
#pragma unroll
  for (int i = 0; i < 4; ++i)
#pragma unroll
    for (int j = 0; j < 4; ++j) acc[i][j] = (floatx4)(0.0f);

  const float4* h4 = (const float4*)h;

  // ---------------- Layer 1: relu([h[dst]|h[src]] @ W1), K=512 ----------------
  for (int kc = 0; kc < 8; ++kc) {
    __syncthreads();
    // Stage A: gather 64 rows x 64 bf16 (inline fp32->bf16), swizzled
#pragma unroll
    for (int it = 0; it < 2; ++it) {
      int uu = it * 256 + t;
      int rt = uu >> 3, c = uu & 7;
      int node = sm.u.l1.ioff[(kc >= 4 ? 64 : 0) + rt];
      int f4i  = node * 64 + (kc & 3) * 16 + c * 2;
      float4 v0 = h4[f4i];
      float4 v1 = h4[f4i + 1];
      short8 s;
      s[0] = (short)f2bf(v0.x); s[1] = (short)f2bf(v0.y);
      s[2] = (short)f2bf(v0.z); s[3] = (short)f2bf(v0.w);
      s[4] = (short)f2bf(v1.x); s[5] = (short)f2bf(v1.y);
      s[6] = (short)f2bf(v1.z); s[7] = (short)f2bf(v1.w);
      sm.u.l1.A[rt * 8 + (c ^ (rt & 7))] = s;
    }
    // Stage B: 32 KB contiguous of pre-swizzled W1T via async global->LDS
    {
      const char* gb = (const char*)W1T + kc * 32768;
      char* lb = (char*)&sm.B[0];
#pragma unroll
      for (int cc = 0; cc < 8; ++cc) {
        int off = (cc * 4 + w) * 1024;
        gload_lds16(gb + off + lane * 16, lb + off);
      }
    }
    __syncthreads();
#pragma unroll
    for (int kk = 0; kk < 2; ++kk) {
      int c = kk * 4 + lq;
      short8 af[4], bfr[4];
#pragma unroll
      for (int i = 0; i < 4; ++i) {
        int r = i * 16 + lm;
        af[i] = sm.u.l1.A[r * 8 + (c ^ (r & 7))];
      }
#pragma unroll
      for (int j = 0; j < 4; ++j) {
        int n = w * 64 + j * 16 + lm;
        bfr[j] = sm.B[n * 8 + (c ^ (n & 7))];
      }
#pragma unroll
      for (int i = 0; i < 4; ++i)
#pragma unroll
        for (int j = 0; j < 4; ++j)
          acc[i][j] = __builtin_amdgcn_mfma_f32_16x16x32_bf16(af[i], bfr[j], acc[i][j], 0, 0, 0);
    }
  }

  __syncthreads();  // A/ioff dead from here; X overlays the union
  // Epilogue 1: relu -> X (bf16, swizzled). C/D map: col=lane&15, row=quad*4+reg.
#pragma unroll
  for (int i = 0; i < 4; ++i) {
    int row0 = i * 16 + lq * 4;
#pragma unroll
    for (int j = 0; j < 4; ++j) {
      int col = w * 64 + j * 16 + lm;
      int cch = col >> 3, ce = col & 7;
#pragma unroll
      for (int rg = 0; rg < 4; ++rg) {
        int row = row0 + rg;
        float v = acc[i][j][rg];
        v = v > 0.0f ? v : 0.0f;
        sm.u.X[row * 256 + ((cch ^ (row & 7)) << 3) + ce] = f2bf(v);
      }
    }
  }

#pragma unroll
  for (int i = 0; i < 4; ++i)
#pragma unroll
    for (int j = 0; j < 4; ++j) acc[i][j] = (floatx4)(0.0f);

  // ---------------- Layer 2: relu(X @ W2), K=256 (A comes straight from X) ----
  for (int kc = 0; kc < 4; ++kc) {
    __syncthreads();
    {
      const char* gb = (const char*)W2T + kc * 32768;
      char* lb = (char*)&sm.B[0];
#pragma unroll
      for (int cc = 0; cc < 8; ++cc) {
        int off = (cc * 4 + w) * 1024;
        gload_lds16(gb + off + lane * 16, lb + off);
      }
    }
    __syncthreads();
#pragma unroll
    for (int kk = 0; kk < 2; ++kk) {
      int cx = kc * 8 + kk * 4 + lq;   // 16B chunk within 512B X row
      int cb = kk * 4 + lq;            // chunk within B tile
      short8 af[4], bfr[4];
#pragma unroll
      for (int i = 0; i < 4; ++i) {
        int r = i * 16 + lm;
        af[i] = *(const short8*)&sm.u.X[r * 256 + ((cx ^ (r & 7)) << 3)];
      }
#pragma unroll
      for (int j = 0; j < 4; ++j) {
        int n = w * 64 + j * 16 + lm;
        bfr[j] = sm.B[n * 8 + (cb ^ (n & 7))];
      }
#pragma unroll
      for (int i = 0; i < 4; ++i)
#pragma unroll
        for (int j = 0; j < 4; ++j)
          acc[i][j] = __builtin_amdgcn_mfma_f32_16x16x32_bf16(af[i], bfr[j], acc[i][j], 0, 0, 0);
    }
  }

  __syncthreads();  // everyone done reading X and B
  // Epilogue 2: relu -> X; stage W3 fp32 into the (dead) B buffer
#pragma unroll
  for (int i = 0; i < 4; ++i) {
    int row0 = i * 16 + lq * 4;
#pragma unroll
    for (int j = 0; j < 4; ++j) {
      int col = w * 64 + j * 16 + lm;
      int cch = col >> 3, ce = col & 7;
#pragma unroll
      for (int rg = 0; rg < 4; ++rg) {
        int row = row0 + rg;
        float v = acc[i][j][rg];
        v = v > 0.0f ? v : 0.0f;
        sm.u.X[row * 256 + ((cch ^ (row & 7)) << 3) + ce] = f2bf(v);
      }
    }
  }
  float* w3s = (float*)&sm.B[0];
  w3s[t] = W3[t];
  w3s[t + 256] = W3[t + 256];
  __syncthreads();

  // ---------------- Layer 3: out = X @ W3 (fp32 VALU, N=2) --------------------
  {
    int r = t >> 2, o = (t >> 1) & 1, hh = t & 1;  // half of K per thread
    float s = 0.0f;
#pragma unroll
    for (int it = 0; it < 16; ++it) {
      int c = hh * 16 + it;  // logical 8-elem chunk
      short8 xv = *(const short8*)&sm.u.X[r * 256 + ((c ^ (r & 7)) << 3)];
#pragma unroll
      for (int e = 0; e < 8; ++e)
        s += bf2f((unsigned short)xv[e]) * w3s[((c << 3) + e) * 2 + o];
    }
    s += __shfl_xor(s, 1);
    if (hh == 0) out[(m0 + r) * 2 + o] = s;
  }
}

extern "C" void kernel_launch(void* const* d_in, const int* in_sizes, int n_in,
                              void* d_out, int out_size, void* d_ws, size_t ws_size,
                              hipStream_t stream) {
  const float* h  = (const float*)d_in[0];
  const int*   dst = (const int*)d_in[1];
  const int*   src = (const int*)d_in[2];
  const float* W1 = (const float*)d_in[3];
  const float* W2 = (const float*)d_in[4];
  const float* W3 = (const float*)d_in[5];
  float* out = (float*)d_out;

  unsigned short* W1T = (unsigned short*)d_ws;            // 512*256 bf16 = 256 KB
  unsigned short* W2T = W1T + 512 * 256;                  // 256*256 bf16 = 128 KB

  wcvt_kernel<<<512, 256, 0, stream>>>(W1, W1T, 512 * 256);
  wcvt_kernel<<<256, 256, 0, stream>>>(W2, W2T, 256 * 256);
  edge_mlp_kernel<<<8192, 256, 0, stream>>>(h, dst, src, W1T, W2T, W3, out);
}

// Round 2
// 464.544 us; speedup vs baseline: 1.0826x; 1.0826x over previous
//
#include <hip/hip_runtime.h>
#include <stdint.h>

typedef __attribute__((ext_vector_type(8))) short short8;
typedef __attribute__((ext_vector_type(4))) float floatx4;

__device__ __forceinline__ unsigned short f2bf(float x) {
  unsigned int u = __float_as_uint(x);
  u += 0x7fffu + ((u >> 16) & 1u);   // RNE
  return (unsigned short)(u >> 16);
}
__device__ __forceinline__ float bf2f(unsigned short b) {
  return __uint_as_float(((unsigned int)b) << 16);
}

// h fp32 [N,256] -> bf16 [N,256] row-major (8 elems/thread)
__global__ void hcvt_kernel(const float* __restrict__ h,
                            unsigned short* __restrict__ o, int total8) {
  int u = blockIdx.x * 256 + threadIdx.x;
  if (u >= total8) return;
  const float4* h4 = (const float4*)h;
  float4 v0 = h4[u * 2], v1 = h4[u * 2 + 1];
  short8 s;
  s[0] = (short)f2bf(v0.x); s[1] = (short)f2bf(v0.y);
  s[2] = (short)f2bf(v0.z); s[3] = (short)f2bf(v0.w);
  s[4] = (short)f2bf(v1.x); s[5] = (short)f2bf(v1.y);
  s[6] = (short)f2bf(v1.z); s[7] = (short)f2bf(v1.w);
  ((short8*)o)[u] = s;
}

// W [K][256] fp32 -> fragment-major bf16:
// flat u = ((k32*256 + n)*4 + kq)*8 + j  holds  W[k32*32 + kq*8 + j][n].
// A wave's B-fragment load (lane: n=ntile+lm, kq=lq) is then a coalesced 1 KB.
__global__ void wfrag_kernel(const float* __restrict__ W,
                             unsigned short* __restrict__ out, int total) {
  int u = blockIdx.x * 256 + threadIdx.x;
  if (u >= total) return;
  int j   = u & 7;
  int kq  = (u >> 3) & 3;
  int n   = (u >> 5) & 255;
  int k32 = u >> 13;
  int k   = k32 * 32 + kq * 8 + j;
  out[u] = f2bf(W[k * 256 + n]);
}

// LDS: A = 64 rows x 512 bf16 (64 KB), 16B-chunk swizzle slot = c ^ (r&7).
// X (layer outputs, 64 x 256 bf16, 32 KB) overlays A after layer 1.
// + w3 (2 KB fp32) + ioff (512 B). Total ~68 KB -> 2 blocks/CU.
template <bool HBF>
__global__ __launch_bounds__(256, 2)
void edge_mlp_kernel(const void* __restrict__ hsrc,
                     const int* __restrict__ dst,
                     const int* __restrict__ src,
                     const unsigned short* __restrict__ W1F,
                     const unsigned short* __restrict__ W2F,
                     const float* __restrict__ W3,
                     float* __restrict__ out) {
  __shared__ unsigned short A[64 * 512];
  __shared__ float w3s[512];
  __shared__ int ioff[128];
  unsigned short* X = A;  // overlay, row stride 256

  const int t    = threadIdx.x;
  const int lane = t & 63;
  const int w    = t >> 6;      // wave id -> N columns w*64..+64
  const int lq   = lane >> 4;
  const int lm   = lane & 15;
  const int m0   = blockIdx.x * 64;

  if (t < 64)       ioff[t] = dst[m0 + t];
  else if (t < 128) ioff[t] = src[m0 + t - 64];
  w3s[t] = W3[t];
  w3s[t + 256] = W3[t + 256];
  __syncthreads();

  // ---- Stage whole A tile: 64 pair-rows x 512 bf16 (chunks 0..31 dst, 32..63 src)
  {
    const int c    = lane;           // 16B chunk within row
    const int half = (c >= 32) ? 64 : 0;
    const int cc   = c & 31;
#pragma unroll
    for (int it = 0; it < 16; ++it) {
      int r = it * 4 + w;            // wave-uniform row -> coalesced 512B segments
      int node = ioff[half + r];
      short8 v;
      if (HBF) {
        v = ((const short8*)hsrc)[node * 32 + cc];
      } else {
        const float4* h4 = (const float4*)hsrc;
        float4 v0 = h4[node * 64 + cc * 2];
        float4 v1 = h4[node * 64 + cc * 2 + 1];
        v[0] = (short)f2bf(v0.x); v[1] = (short)f2bf(v0.y);
        v[2] = (short)f2bf(v0.z); v[3] = (short)f2bf(v0.w);
        v[4] = (short)f2bf(v1.x); v[5] = (short)f2bf(v1.y);
        v[6] = (short)f2bf(v1.z); v[7] = (short)f2bf(v1.w);
      }
      *(short8*)&A[r * 512 + ((c ^ (r & 7)) << 3)] = v;
    }
  }

  floatx4 acc[4][4];
#pragma unroll
  for (int i = 0; i < 4; ++i)
#pragma unroll
    for (int j = 0; j < 4; ++j) acc[i][j] = (floatx4)(0.0f);

  __syncthreads();

  // ---- Layer 1: K=512, 16 k-steps of 32, B from global (L2), no inner barriers
  const short8* B1 = (const short8*)W1F;
  const short8* B2 = (const short8*)W2F;

  auto loadB1 = [&](short8* b, int k32) {
#pragma unroll
    for (int jt = 0; jt < 4; ++jt)
      b[jt] = B1[(k32 * 256 + w * 64 + jt * 16 + lm) * 4 + lq];
  };
  auto stepL1 = [&](int k32, const short8* b) {
    short8 af[4];
#pragma unroll
    for (int i = 0; i < 4; ++i) {
      int r = i * 16 + lm;
      int c = k32 * 4 + lq;
      af[i] = *(const short8*)&A[r * 512 + ((c ^ (r & 7)) << 3)];
    }
#pragma unroll
    for (int i = 0; i < 4; ++i)
#pragma unroll
      for (int j = 0; j < 4; ++j)
        acc[i][j] = __builtin_amdgcn_mfma_f32_16x16x32_bf16(af[i], b[j], acc[i][j], 0, 0, 0);
  };

  {
    short8 b0[4], b1[4];
    loadB1(b0, 0);
#pragma unroll
    for (int k2 = 0; k2 < 8; ++k2) {
      loadB1(b1, k2 * 2 + 1);
      stepL1(k2 * 2, b0);
      loadB1(b0, (k2 * 2 + 2) & 15);   // wraps to 0 on last iter (dead)
      stepL1(k2 * 2 + 1, b1);
    }
  }

  __syncthreads();  // all A reads done; X overlays A
  // Epilogue 1: relu -> X bf16. C/D map: col=lane&15, row=quad*4+reg.
#pragma unroll
  for (int i = 0; i < 4; ++i) {
    int row0 = i * 16 + lq * 4;
#pragma unroll
    for (int j = 0; j < 4; ++j) {
      int col = w * 64 + j * 16 + lm;
      int cch = col >> 3, ce = col & 7;
#pragma unroll
      for (int rg = 0; rg < 4; ++rg) {
        int row = row0 + rg;
        float v = acc[i][j][rg];
        v = v > 0.0f ? v : 0.0f;
        X[row * 256 + (((cch ^ (row & 7)) << 3) | ce)] = f2bf(v);
      }
    }
  }
#pragma unroll
  for (int i = 0; i < 4; ++i)
#pragma unroll
    for (int j = 0; j < 4; ++j) acc[i][j] = (floatx4)(0.0f);
  __syncthreads();

  // ---- Layer 2: K=256, 8 k-steps, A from X (LDS), B from global
  auto loadB2 = [&](short8* b, int k32) {
#pragma unroll
    for (int jt = 0; jt < 4; ++jt)
      b[jt] = B2[(k32 * 256 + w * 64 + jt * 16 + lm) * 4 + lq];
  };
  auto stepL2 = [&](int k32, const short8* b) {
    short8 af[4];
#pragma unroll
    for (int i = 0; i < 4; ++i) {
      int r = i * 16 + lm;
      int c = k32 * 4 + lq;
      af[i] = *(const short8*)&X[r * 256 + ((c ^ (r & 7)) << 3)];
    }
#pragma unroll
    for (int i = 0; i < 4; ++i)
#pragma unroll
      for (int j = 0; j < 4; ++j)
        acc[i][j] = __builtin_amdgcn_mfma_f32_16x16x32_bf16(af[i], b[j], acc[i][j], 0, 0, 0);
  };

  {
    short8 b0[4], b1[4];
    loadB2(b0, 0);
#pragma unroll
    for (int k2 = 0; k2 < 4; ++k2) {
      loadB2(b1, k2 * 2 + 1);
      stepL2(k2 * 2, b0);
      loadB2(b0, (k2 * 2 + 2) & 7);
      stepL2(k2 * 2 + 1, b1);
    }
  }

  __syncthreads();
  // Epilogue 2: relu -> X
#pragma unroll
  for (int i = 0; i < 4; ++i) {
    int row0 = i * 16 + lq * 4;
#pragma unroll
    for (int j = 0; j < 4; ++j) {
      int col = w * 64 + j * 16 + lm;
      int cch = col >> 3, ce = col & 7;
#pragma unroll
      for (int rg = 0; rg < 4; ++rg) {
        int row = row0 + rg;
        float v = acc[i][j][rg];
        v = v > 0.0f ? v : 0.0f;
        X[row * 256 + (((cch ^ (row & 7)) << 3) | ce)] = f2bf(v);
      }
    }
  }
  __syncthreads();

  // ---- Layer 3: out = X @ W3 (fp32 VALU, N=2)
  {
    int r = t >> 2, o = (t >> 1) & 1, hh = t & 1;
    float s = 0.0f;
#pragma unroll
    for (int it = 0; it < 16; ++it) {
      int c = hh * 16 + it;
      short8 xv = *(const short8*)&X[r * 256 + ((c ^ (r & 7)) << 3)];
#pragma unroll
      for (int e = 0; e < 8; ++e)
        s += bf2f((unsigned short)xv[e]) * w3s[((c << 3) + e) * 2 + o];
    }
    s += __shfl_xor(s, 1);
    if (hh == 0) out[(m0 + r) * 2 + o] = s;
  }
}

extern "C" void kernel_launch(void* const* d_in, const int* in_sizes, int n_in,
                              void* d_out, int out_size, void* d_ws, size_t ws_size,
                              hipStream_t stream) {
  const float* h   = (const float*)d_in[0];
  const int*   dst = (const int*)d_in[1];
  const int*   src = (const int*)d_in[2];
  const float* W1  = (const float*)d_in[3];
  const float* W2  = (const float*)d_in[4];
  const float* W3  = (const float*)d_in[5];
  float* out = (float*)d_out;

  const int h_elems  = in_sizes[0];           // NUM_NODES * 256
  const int n_pairs  = in_sizes[1];           // P
  const int grid     = n_pairs / 64;

  const size_t hbf_elems = (size_t)h_elems;
  const bool use_hbf = ws_size >= (hbf_elems + 131072 + 65536) * sizeof(unsigned short);

  unsigned short* HBF = (unsigned short*)d_ws;
  unsigned short* W1F = use_hbf ? HBF + hbf_elems : (unsigned short*)d_ws;
  unsigned short* W2F = W1F + 131072;

  wfrag_kernel<<<512, 256, 0, stream>>>(W1, W1F, 131072);
  wfrag_kernel<<<256, 256, 0, stream>>>(W2, W2F, 65536);

  if (use_hbf) {
    int total8 = h_elems / 8;
    hcvt_kernel<<<(total8 + 255) / 256, 256, 0, stream>>>(h, HBF, total8);
    edge_mlp_kernel<true><<<grid, 256, 0, stream>>>(HBF, dst, src, W1F, W2F, W3, out);
  } else {
    edge_mlp_kernel<false><<<grid, 256, 0, stream>>>(h, dst, src, W1F, W2F, W3, out);
  }
}